// Round 3
// baseline (405.501 us; speedup 1.0000x reference)
//
#include <hip/hip_runtime.h>

// Beam-search step, B=128 K=8 V=50257 L=64 MAXL=128 A=512 D=1024 EOS=2.
// k_rowpass v3: single streaming pass computing sum-exp + per-1KB-segment
// maxima; tau = 9th-largest segment max (provably >= all non-EOS top-8);
// re-read ONLY qualifying segments (~10KB/row, L2/L3-hit) to collect ~12
// candidates; select top-8 exactly. 1024-thr blocks for 100% occupancy.

#define BB 128
#define KK 8
#define VV 50257
#define LL 64
#define MAXLEN 128
#define AA 512
#define DD 1024
#define EOSI 2
#define NTHR 1024
#define NWAVE 16
#define NSEG 256
#define CAP 1024
#define STHR 256

// output offsets (flat floats in d_out)
constexpr size_t O0 = 0;                      // new_cand_scores (B*K)
constexpr size_t O1 = 1024;                   // new_seqs (B*K*65)
constexpr size_t O2 = 67584;                  // parents (B*K)
constexpr size_t O3 = 68608;                  // comp_scores (B*K)
constexpr size_t O4 = 69632;                  // comp_seqs (B*K*128)
constexpr size_t O5 = 200704;                 // comp_len (B*K)
constexpr size_t O6 = 201728;                 // ctx (B*K*512)
constexpr size_t O7 = 726016;                 // rnn1 (B*K*1024)
constexpr size_t O8 = 1774592;                // rnn2 (B*K*1024)

__device__ __forceinline__ bool better(float v2, int i2, float v1, int i1) {
  // jax.lax.top_k order: descending value, ties -> lower index first
  return (v2 > v1) || (v2 == v1 && i2 < i1);
}

// ---------------- Kernel 1: per-(b,k)-row stats + top-8 via segment filter ----------------
__global__ __launch_bounds__(NTHR) void k_rowpass(
    const float* __restrict__ logits,
    float* __restrict__ ws_max, float* __restrict__ ws_lse,
    float* __restrict__ ws_eos,
    float* __restrict__ ws_tv, int* __restrict__ ws_ti) {
  const int r = blockIdx.x;              // r = b*K + k
  const int tid = threadIdx.x;
  const int lane = tid & 63, wid = tid >> 6;
  const float* __restrict__ row = logits + (size_t)r * VV;

  __shared__ float segmax[NSEG];
  __shared__ float redS[NWAVE], redM[NWAVE];
  __shared__ float stau;
  __shared__ int scnt, snq;
  __shared__ float cv[CAP];
  __shared__ int ci[CAP];
  __shared__ int qseg[NSEG];
  __shared__ float rv4[NWAVE]; __shared__ int ri4[NWAVE], rl4[NWAVE];

  if (tid < NSEG) segmax[tid] = -INFINITY;
  if (tid == 0) { ws_eos[r] = row[EOSI]; scnt = 0; snq = 0; }
  __syncthreads();

  // alignment: (r*VV) mod 4 == r mod 4  (VV % 4 == 1)
  const int pre = (4 - (r & 3)) & 3;
  const int nvec = (VV - pre) >> 2;
  const int rem = VV - pre - (nvec << 2);
  const float4* __restrict__ vrow = (const float4*)(row + pre);
  const int niter = (nvec + NTHR - 1) / NTHR;   // 13

  float m = -INFINITY, s0 = 0.0f, s1 = 0.0f;

  // prologue/epilogue scalars (<=6 total): fold into sum/max, always candidates
  if (tid < pre) {
    float x = row[tid];
    s0 += __expf(x); m = fmaxf(m, x);
    int p = atomicAdd(&scnt, 1); cv[p] = x; ci[p] = tid;
  }
  if (tid >= 8 && tid < 8 + rem) {
    int e = pre + (nvec << 2) + (tid - 8);
    float x = row[e];
    s0 += __expf(x); m = fmaxf(m, x);
    int p = atomicAdd(&scnt, 1); cv[p] = x; ci[p] = e;
  }

  // -------- pass A: branchless sum-exp + per-segment (1KB) maxima --------
  for (int i = 0; i < niter; ++i) {
    const int vi = i * NTHR + tid;
    float mloc = -INFINITY;
    if (vi < nvec) {
      float4 x = vrow[vi];
      s0 += __expf(x.x); s1 += __expf(x.y);
      s0 += __expf(x.z); s1 += __expf(x.w);
      mloc = fmaxf(fmaxf(x.x, x.y), fmaxf(x.z, x.w));
      m = fmaxf(m, mloc);
    }
    float wm = mloc;
    for (int off = 32; off; off >>= 1) wm = fmaxf(wm, __shfl_down(wm, off));
    if (lane == 0) segmax[i * NWAVE + wid] = wm;   // seg id < 13*16=208 < 256
  }

  float s = s0 + s1;
  for (int off = 32; off; off >>= 1) {
    s += __shfl_down(s, off);
    m = fmaxf(m, __shfl_down(m, off));
  }
  if (lane == 0) { redS[wid] = s; redM[wid] = m; }
  __syncthreads();
  if (tid == 0) {
    float S = 0.0f, M = -INFINITY;
    for (int w = 0; w < NWAVE; ++w) { S += redS[w]; M = fmaxf(M, redM[w]); }
    ws_max[r] = M;
    ws_lse[r] = logf(S) - M;     // == log(sum exp(x - M)) up to rounding
  }

  // -------- tau = 9th largest of the segment maxima (wave 0) --------
  // >=9 segments have max >= tau  =>  >=9 elements >= tau  =>  >=8 non-EOS
  // elements >= tau  =>  every non-EOS top-8 element >= tau.  Any x >= tau
  // lies in a segment whose max >= tau (qualifying), so scanning qualifying
  // segments collects an exact superset of the non-EOS top-8.
  if (wid == 0) {
    float v0 = segmax[lane], v1 = segmax[lane + 64];
    float v2 = segmax[lane + 128], v3 = segmax[lane + 192];
    float tau = -INFINITY;
    for (int rr = 0; rr < 9; ++rr) {
      float lm = fmaxf(fmaxf(v0, v1), fmaxf(v2, v3));
      float wm = lm;
      for (int off = 32; off; off >>= 1) wm = fmaxf(wm, __shfl_down(wm, off));
      wm = __shfl(wm, 0);
      tau = wm;
      unsigned long long msk = __ballot(lm == wm);
      int first = __ffsll(msk) - 1;
      if (lane == first) {
        if (v0 == wm) v0 = -INFINITY;
        else if (v1 == wm) v1 = -INFINITY;
        else if (v2 == wm) v2 = -INFINITY;
        else v3 = -INFINITY;
      }
    }
    if (lane == 0) stau = tau;
  }
  __syncthreads();
  const float tau = stau;

  // -------- enumerate qualifying segments --------
  if (tid < NSEG && segmax[tid] >= tau) {
    int p = atomicAdd(&snq, 1);
    qseg[p] = tid;
  }
  __syncthreads();
  const int nq = snq;

  // -------- pass B: re-read ONLY qualifying segments (1KB each) --------
  for (int j = wid; j < nq; j += NWAVE) {
    const int vi = qseg[j] * 64 + lane;
    if (vi < nvec) {
      float4 x = vrow[vi];
      const int i0 = pre + (vi << 2);
      if (x.x >= tau) { int p = atomicAdd(&scnt, 1); if (p < CAP) { cv[p] = x.x; ci[p] = i0; } }
      if (x.y >= tau) { int p = atomicAdd(&scnt, 1); if (p < CAP) { cv[p] = x.y; ci[p] = i0 + 1; } }
      if (x.z >= tau) { int p = atomicAdd(&scnt, 1); if (p < CAP) { cv[p] = x.z; ci[p] = i0 + 2; } }
      if (x.w >= tau) { int p = atomicAdd(&scnt, 1); if (p < CAP) { cv[p] = x.w; ci[p] = i0 + 3; } }
    }
  }
  __syncthreads();

  // -------- top-8 (value desc, index asc), excluding EOS --------
  const int n = scnt < CAP ? scnt : CAP;
  for (int sel = 0; sel < 8; ++sel) {
    float bv = -INFINITY; int bi = 0x7fffffff; int bl = -1;
    for (int j = tid; j < n; j += NTHR) {
      float v = cv[j]; int idx = ci[j];
      if (idx != EOSI && better(v, idx, bv, bi)) { bv = v; bi = idx; bl = j; }
    }
    for (int off = 32; off; off >>= 1) {
      float v2 = __shfl_down(bv, off);
      int i2 = __shfl_down(bi, off);
      int l2 = __shfl_down(bl, off);
      if (better(v2, i2, bv, bi)) { bv = v2; bi = i2; bl = l2; }
    }
    if (lane == 0) { rv4[wid] = bv; ri4[wid] = bi; rl4[wid] = bl; }
    __syncthreads();
    if (tid == 0) {
      float fv = rv4[0]; int fi = ri4[0], fl = rl4[0];
      for (int w = 1; w < NWAVE; ++w)
        if (better(rv4[w], ri4[w], fv, fi)) { fv = rv4[w]; fi = ri4[w]; fl = rl4[w]; }
      ws_tv[r * 8 + sel] = fv;
      ws_ti[r * 8 + sel] = fi;
      if (fl >= 0) cv[fl] = -INFINITY;
    }
    __syncthreads();
  }
}

// ---------------- Kernel 2: per-batch merge + small outputs ----------------
__global__ __launch_bounds__(STHR) void k_select(
    const float* __restrict__ cand_scores, const int* __restrict__ cand_seqs,
    const float* __restrict__ completed_scores, const int* __restrict__ completed_seqs,
    const int* __restrict__ completed_length,
    const float* __restrict__ ws_max, const float* __restrict__ ws_lse,
    const float* __restrict__ ws_eos, const float* __restrict__ ws_tv,
    const int* __restrict__ ws_ti, int* __restrict__ ws_par,
    float* __restrict__ out) {
  const int b = blockIdx.x;
  const int tid = threadIdx.x;
  __shared__ float sh_mx[KK], sh_lse[KK], sh_cand[KK];
  __shared__ float sh_ncs[KK]; __shared__ int sh_par[KK], sh_sym[KK];
  __shared__ float sh_cs[KK];  __shared__ int sh_clen[KK], sh_cind[KK];
  if (tid < KK) {
    sh_mx[tid] = ws_max[b * KK + tid];
    sh_lse[tid] = ws_lse[b * KK + tid];
    sh_cand[tid] = cand_scores[b * KK + tid];
  }
  __syncthreads();
  if (tid < 64) {
    const int lane = tid;
    // ---- candidate top-8 over 8 rows x 8 entries ----
    const int k = lane >> 3, j = lane & 7;
    float x = ws_tv[(b * KK + k) * 8 + j];
    int v = ws_ti[(b * KK + k) * 8 + j];
    // match jax association: ((x - max) - lse) + cand
    float val = ((x - sh_mx[k]) - sh_lse[k]) + sh_cand[k];
    int flat = k * VV + v;
    if (v == 0x7fffffff) { val = -INFINITY; flat = 0x7fffffff; }
    for (int sel = 0; sel < 8; ++sel) {
      float bv = val; int bi = flat; int bl = lane;
      for (int off = 32; off; off >>= 1) {
        float v2 = __shfl_down(bv, off);
        int i2 = __shfl_down(bi, off);
        int l2 = __shfl_down(bl, off);
        if (better(v2, i2, bv, bi)) { bv = v2; bi = i2; bl = l2; }
      }
      int wl = __shfl(bl, 0);
      if (lane == wl) {
        sh_ncs[sel] = val; sh_par[sel] = flat / VV; sh_sym[sel] = flat % VV;
        val = -INFINITY; flat = 0x7fffffff;
      }
    }
    // ---- completed top-8 over 16 rescaled scores ----
    float cs; int clen;
    if (lane < KK) {
      cs = completed_scores[b * KK + lane];
      clen = completed_length[b * KK + lane];
    } else if (lane < 2 * KK) {
      int k2 = lane - KK;
      cs = ((ws_eos[b * KK + k2] - sh_mx[k2]) - sh_lse[k2]) + sh_cand[k2];
      clen = LL + 1;
    } else { cs = -INFINITY; clen = 1; }
    float rsc = (lane < 2 * KK) ? cs / (float)clen : -INFINITY;
    for (int sel = 0; sel < 8; ++sel) {
      float bv = rsc; int bi = lane;
      for (int off = 32; off; off >>= 1) {
        float v2 = __shfl_down(bv, off);
        int i2 = __shfl_down(bi, off);
        if (better(v2, i2, bv, bi)) { bv = v2; bi = i2; }
      }
      int wl = __shfl(bi, 0);
      if (lane == wl) {
        sh_cs[sel] = cs; sh_clen[sel] = clen; sh_cind[sel] = lane;
        rsc = -INFINITY;
      }
    }
  }
  __syncthreads();
  if (tid < KK) {
    out[O0 + (size_t)b * KK + tid] = sh_ncs[tid];
    out[O2 + (size_t)b * KK + tid] = (float)sh_par[tid];
    out[O3 + (size_t)b * KK + tid] = sh_cs[tid];
    out[O5 + (size_t)b * KK + tid] = (float)sh_clen[tid];
    ws_par[b * KK + tid] = sh_par[tid];
  }
  // new_seqs: K * (L+1), gather parent prefix + new symbol
  for (int t = tid; t < KK * (LL + 1); t += STHR) {
    int i = t / (LL + 1), pos = t - i * (LL + 1);
    int val;
    if (pos < LL) val = cand_seqs[((size_t)b * KK + sh_par[i]) * LL + pos];
    else val = sh_sym[i];
    out[O1 + ((size_t)b * KK + i) * (LL + 1) + pos] = (float)val;
  }
  // comp_seqs: K * MAXL
  for (int t = tid; t < KK * MAXLEN; t += STHR) {
    int i = t >> 7, pos = t & 127;
    int c = sh_cind[i];
    int val;
    if (c < KK) val = completed_seqs[((size_t)b * KK + c) * MAXLEN + pos];
    else {
      int k2 = c - KK;
      val = (pos < LL) ? cand_seqs[((size_t)b * KK + k2) * LL + pos] : EOSI;
    }
    out[O4 + ((size_t)b * KK + i) * MAXLEN + pos] = (float)val;
  }
}

// ---------------- Kernel 3: decoder-state gather (float4 copies) ----------------
__global__ __launch_bounds__(STHR) void k_gather(
    const float* __restrict__ ctx, const float* __restrict__ r1,
    const float* __restrict__ r2, const int* __restrict__ ws_par,
    float* __restrict__ out) {
  const int r = blockIdx.x;             // b*K + k
  const int b = r >> 3;
  const int src = (b << 3) + ws_par[r];
  const int tid = threadIdx.x;
  {
    const float4* s4 = (const float4*)(ctx + (size_t)src * AA);
    float4* d4 = (float4*)(out + O6 + (size_t)r * AA);
    for (int i = tid; i < AA / 4; i += STHR) d4[i] = s4[i];
  }
  {
    const float4* s4 = (const float4*)(r1 + (size_t)src * DD);
    float4* d4 = (float4*)(out + O7 + (size_t)r * DD);
    for (int i = tid; i < DD / 4; i += STHR) d4[i] = s4[i];
  }
  {
    const float4* s4 = (const float4*)(r2 + (size_t)src * DD);
    float4* d4 = (float4*)(out + O8 + (size_t)r * DD);
    for (int i = tid; i < DD / 4; i += STHR) d4[i] = s4[i];
  }
}

extern "C" void kernel_launch(void* const* d_in, const int* in_sizes, int n_in,
                              void* d_out, int out_size, void* d_ws, size_t ws_size,
                              hipStream_t stream) {
  const float* logits = (const float*)d_in[0];
  const float* cand_scores = (const float*)d_in[1];
  const int* cand_seqs = (const int*)d_in[2];
  const float* completed_scores = (const float*)d_in[3];
  const int* completed_seqs = (const int*)d_in[4];
  const int* completed_length = (const int*)d_in[5];
  const float* dctx = (const float*)d_in[6];
  const float* drnn1 = (const float*)d_in[7];
  const float* drnn2 = (const float*)d_in[8];
  float* out = (float*)d_out;

  float* ws_max = (float*)d_ws;                 // 1024
  float* ws_lse = ws_max + BB * KK;             // 1024
  float* ws_eos = ws_lse + BB * KK;             // 1024
  float* ws_tv = ws_eos + BB * KK;              // 8192
  int* ws_ti = (int*)(ws_tv + BB * KK * 8);     // 8192
  int* ws_par = ws_ti + BB * KK * 8;            // 1024

  k_rowpass<<<BB * KK, NTHR, 0, stream>>>(logits, ws_max, ws_lse, ws_eos, ws_tv, ws_ti);
  k_select<<<BB, STHR, 0, stream>>>(cand_scores, cand_seqs, completed_scores,
                                    completed_seqs, completed_length, ws_max, ws_lse,
                                    ws_eos, ws_tv, ws_ti, ws_par, out);
  k_gather<<<BB * KK, STHR, 0, stream>>>(dctx, drnn1, drnn2, ws_par, out);
}

// Round 4
// 352.281 us; speedup vs baseline: 1.1511x; 1.1511x over previous
//
#include <hip/hip_runtime.h>

// Beam-search step, B=128 K=8 V=50257 L=64 MAXL=128 A=512 D=1024 EOS=2.
// k_rowpass v4: branchless streaming pass A (sum-exp + per-thread max, NO
// in-loop cross-lane ops); tau = 9th-largest per-thread max (provably <=
// true 8th-largest element); pass B rescans ONLY the ~9-12 qualifying
// threads' own elements (~2MB chip-wide, L2-hit) into an LDS pool; exact
// top-8 selection over ~15 candidates. 256-thr blocks, 4 blocks/CU.

#define BB 128
#define KK 8
#define VV 50257
#define LL 64
#define MAXLEN 128
#define AA 512
#define DD 1024
#define EOSI 2
#define NTHR 256
#define NWAVE 4
#define CAP 1024
#define STHR 256

// output offsets (flat floats in d_out)
constexpr size_t O0 = 0;                      // new_cand_scores (B*K)
constexpr size_t O1 = 1024;                   // new_seqs (B*K*65)
constexpr size_t O2 = 67584;                  // parents (B*K)
constexpr size_t O3 = 68608;                  // comp_scores (B*K)
constexpr size_t O4 = 69632;                  // comp_seqs (B*K*128)
constexpr size_t O5 = 200704;                 // comp_len (B*K)
constexpr size_t O6 = 201728;                 // ctx (B*K*512)
constexpr size_t O7 = 726016;                 // rnn1 (B*K*1024)
constexpr size_t O8 = 1774592;                // rnn2 (B*K*1024)

__device__ __forceinline__ bool better(float v2, int i2, float v1, int i1) {
  // jax.lax.top_k order: descending value, ties -> lower index first
  return (v2 > v1) || (v2 == v1 && i2 < i1);
}

// ---------------- Kernel 1: per-(b,k)-row stats + top-8 via thread filter ----------------
__global__ __launch_bounds__(NTHR) void k_rowpass(
    const float* __restrict__ logits,
    float* __restrict__ ws_max, float* __restrict__ ws_lse,
    float* __restrict__ ws_eos,
    float* __restrict__ ws_tv, int* __restrict__ ws_ti) {
  const int r = blockIdx.x;              // r = b*K + k
  const int tid = threadIdx.x;
  const int lane = tid & 63, wid = tid >> 6;
  const float* __restrict__ row = logits + (size_t)r * VV;

  __shared__ float sm[NTHR];             // per-thread maxima
  __shared__ float redS[NWAVE], redM[NWAVE];
  __shared__ float stau;
  __shared__ int scnt;
  __shared__ float cv[CAP];
  __shared__ int ci[CAP];
  __shared__ float rv4[NWAVE]; __shared__ int ri4[NWAVE], rl4[NWAVE];

  if (tid == 0) { ws_eos[r] = row[EOSI]; scnt = 0; }
  __syncthreads();

  // alignment: (r*VV) mod 4 == r mod 4  (VV % 4 == 1)
  const int pre = (4 - (r & 3)) & 3;
  const int nvec = (VV - pre) >> 2;
  const int rem = VV - pre - (nvec << 2);
  const float4* __restrict__ vrow = (const float4*)(row + pre);

  float m = -INFINITY, s0 = 0.0f, s1 = 0.0f;

  // prologue/epilogue scalars (<=6 total, all handled by wave 0): fold into
  // sum/max and force-collect as candidates (exempt from the tau filter).
  if (tid < pre) {
    float x = row[tid];
    s0 += __expf(x); m = fmaxf(m, x);
    int p = atomicAdd(&scnt, 1); cv[p] = x; ci[p] = tid;
  }
  if (tid >= 8 && tid < 8 + rem) {
    int e = pre + (nvec << 2) + (tid - 8);
    float x = row[e];
    s0 += __expf(x); m = fmaxf(m, x);
    int p = atomicAdd(&scnt, 1); cv[p] = x; ci[p] = e;
  }

  // -------- pass A: branchless sum-exp + per-thread max (pure VALU) --------
#pragma unroll 4
  for (int i = tid; i < nvec; i += NTHR) {
    float4 x = vrow[i];
    s0 += __expf(x.x); s1 += __expf(x.y);
    s0 += __expf(x.z); s1 += __expf(x.w);
    m = fmaxf(fmaxf(x.x, x.y), m);
    m = fmaxf(fmaxf(x.z, x.w), m);
  }
  sm[tid] = m;                            // per-thread max (kept in m too)
  float s = s0 + s1;
  float mr = m;
  for (int off = 32; off; off >>= 1) {
    s += __shfl_down(s, off);
    mr = fmaxf(mr, __shfl_down(mr, off));
  }
  if (lane == 0) { redS[wid] = s; redM[wid] = mr; }
  __syncthreads();
  if (tid == 0) {
    float S = (redS[0] + redS[1]) + (redS[2] + redS[3]);
    float M = fmaxf(fmaxf(redM[0], redM[1]), fmaxf(redM[2], redM[3]));
    ws_max[r] = M;
    ws_lse[r] = logf(S) - M;   // == log(sum exp(x - M)) up to rounding
  }

  // -------- tau = 9th largest of the 256 per-thread maxima (wave 0) --------
  // At most 8 thread-maxima can exceed the true 8th-largest element, so the
  // 9th-largest thread-max <= true 8th-largest value; filtering >= tau keeps
  // all top-8, and >=9 distinct elements >= tau exist (>=8 non-EOS).
  if (wid == 0) {
    float v0 = sm[lane], v1 = sm[lane + 64], v2 = sm[lane + 128], v3 = sm[lane + 192];
    float tau = -INFINITY;
    for (int rr = 0; rr < 9; ++rr) {
      float lm = fmaxf(fmaxf(v0, v1), fmaxf(v2, v3));
      float wm = lm;
      for (int off = 32; off; off >>= 1) wm = fmaxf(wm, __shfl_down(wm, off));
      wm = __shfl(wm, 0);
      tau = wm;
      unsigned long long msk = __ballot(lm == wm);
      int first = __ffsll(msk) - 1;
      if (lane == first) {
        if (v0 == wm) v0 = -INFINITY;
        else if (v1 == wm) v1 = -INFINITY;
        else if (v2 == wm) v2 = -INFINITY;
        else v3 = -INFINITY;
      }
    }
    if (lane == 0) stau = tau;
  }
  __syncthreads();
  const float tau = stau;

  // -------- pass B: only qualifying threads rescan their own elements --------
  // (~9-12 threads/block; their float4s are L2-resident from pass A)
  if (m >= tau) {
    for (int i = tid; i < nvec; i += NTHR) {
      float4 x = vrow[i];
      const int i0 = pre + (i << 2);
      if (x.x >= tau) { int p = atomicAdd(&scnt, 1); if (p < CAP) { cv[p] = x.x; ci[p] = i0; } }
      if (x.y >= tau) { int p = atomicAdd(&scnt, 1); if (p < CAP) { cv[p] = x.y; ci[p] = i0 + 1; } }
      if (x.z >= tau) { int p = atomicAdd(&scnt, 1); if (p < CAP) { cv[p] = x.z; ci[p] = i0 + 2; } }
      if (x.w >= tau) { int p = atomicAdd(&scnt, 1); if (p < CAP) { cv[p] = x.w; ci[p] = i0 + 3; } }
    }
  }
  __syncthreads();

  // -------- top-8 (value desc, index asc), excluding EOS --------
  const int n = scnt < CAP ? scnt : CAP;
  for (int sel = 0; sel < 8; ++sel) {
    float bv = -INFINITY; int bi = 0x7fffffff; int bl = -1;
    for (int j = tid; j < n; j += NTHR) {
      float v = cv[j]; int idx = ci[j];
      if (idx != EOSI && better(v, idx, bv, bi)) { bv = v; bi = idx; bl = j; }
    }
    for (int off = 32; off; off >>= 1) {
      float v2 = __shfl_down(bv, off);
      int i2 = __shfl_down(bi, off);
      int l2 = __shfl_down(bl, off);
      if (better(v2, i2, bv, bi)) { bv = v2; bi = i2; bl = l2; }
    }
    if (lane == 0) { rv4[wid] = bv; ri4[wid] = bi; rl4[wid] = bl; }
    __syncthreads();
    if (tid == 0) {
      float fv = rv4[0]; int fi = ri4[0], fl = rl4[0];
      for (int w = 1; w < NWAVE; ++w)
        if (better(rv4[w], ri4[w], fv, fi)) { fv = rv4[w]; fi = ri4[w]; fl = rl4[w]; }
      ws_tv[r * 8 + sel] = fv;
      ws_ti[r * 8 + sel] = fi;
      if (fl >= 0) cv[fl] = -INFINITY;
    }
    __syncthreads();
  }
}

// ---------------- Kernel 2: per-batch merge + small outputs ----------------
__global__ __launch_bounds__(STHR) void k_select(
    const float* __restrict__ cand_scores, const int* __restrict__ cand_seqs,
    const float* __restrict__ completed_scores, const int* __restrict__ completed_seqs,
    const int* __restrict__ completed_length,
    const float* __restrict__ ws_max, const float* __restrict__ ws_lse,
    const float* __restrict__ ws_eos, const float* __restrict__ ws_tv,
    const int* __restrict__ ws_ti, int* __restrict__ ws_par,
    float* __restrict__ out) {
  const int b = blockIdx.x;
  const int tid = threadIdx.x;
  __shared__ float sh_mx[KK], sh_lse[KK], sh_cand[KK];
  __shared__ float sh_ncs[KK]; __shared__ int sh_par[KK], sh_sym[KK];
  __shared__ float sh_cs[KK];  __shared__ int sh_clen[KK], sh_cind[KK];
  if (tid < KK) {
    sh_mx[tid] = ws_max[b * KK + tid];
    sh_lse[tid] = ws_lse[b * KK + tid];
    sh_cand[tid] = cand_scores[b * KK + tid];
  }
  __syncthreads();
  if (tid < 64) {
    const int lane = tid;
    // ---- candidate top-8 over 8 rows x 8 entries ----
    const int k = lane >> 3, j = lane & 7;
    float x = ws_tv[(b * KK + k) * 8 + j];
    int v = ws_ti[(b * KK + k) * 8 + j];
    // match jax association: ((x - max) - lse) + cand
    float val = ((x - sh_mx[k]) - sh_lse[k]) + sh_cand[k];
    int flat = k * VV + v;
    if (v == 0x7fffffff) { val = -INFINITY; flat = 0x7fffffff; }
    for (int sel = 0; sel < 8; ++sel) {
      float bv = val; int bi = flat; int bl = lane;
      for (int off = 32; off; off >>= 1) {
        float v2 = __shfl_down(bv, off);
        int i2 = __shfl_down(bi, off);
        int l2 = __shfl_down(bl, off);
        if (better(v2, i2, bv, bi)) { bv = v2; bi = i2; bl = l2; }
      }
      int wl = __shfl(bl, 0);
      if (lane == wl) {
        sh_ncs[sel] = val; sh_par[sel] = flat / VV; sh_sym[sel] = flat % VV;
        val = -INFINITY; flat = 0x7fffffff;
      }
    }
    // ---- completed top-8 over 16 rescaled scores ----
    float cs; int clen;
    if (lane < KK) {
      cs = completed_scores[b * KK + lane];
      clen = completed_length[b * KK + lane];
    } else if (lane < 2 * KK) {
      int k2 = lane - KK;
      cs = ((ws_eos[b * KK + k2] - sh_mx[k2]) - sh_lse[k2]) + sh_cand[k2];
      clen = LL + 1;
    } else { cs = -INFINITY; clen = 1; }
    float rsc = (lane < 2 * KK) ? cs / (float)clen : -INFINITY;
    for (int sel = 0; sel < 8; ++sel) {
      float bv = rsc; int bi = lane;
      for (int off = 32; off; off >>= 1) {
        float v2 = __shfl_down(bv, off);
        int i2 = __shfl_down(bi, off);
        if (better(v2, i2, bv, bi)) { bv = v2; bi = i2; }
      }
      int wl = __shfl(bi, 0);
      if (lane == wl) {
        sh_cs[sel] = cs; sh_clen[sel] = clen; sh_cind[sel] = lane;
        rsc = -INFINITY;
      }
    }
  }
  __syncthreads();
  if (tid < KK) {
    out[O0 + (size_t)b * KK + tid] = sh_ncs[tid];
    out[O2 + (size_t)b * KK + tid] = (float)sh_par[tid];
    out[O3 + (size_t)b * KK + tid] = sh_cs[tid];
    out[O5 + (size_t)b * KK + tid] = (float)sh_clen[tid];
    ws_par[b * KK + tid] = sh_par[tid];
  }
  // new_seqs: K * (L+1), gather parent prefix + new symbol
  for (int t = tid; t < KK * (LL + 1); t += STHR) {
    int i = t / (LL + 1), pos = t - i * (LL + 1);
    int val;
    if (pos < LL) val = cand_seqs[((size_t)b * KK + sh_par[i]) * LL + pos];
    else val = sh_sym[i];
    out[O1 + ((size_t)b * KK + i) * (LL + 1) + pos] = (float)val;
  }
  // comp_seqs: K * MAXL
  for (int t = tid; t < KK * MAXLEN; t += STHR) {
    int i = t >> 7, pos = t & 127;
    int c = sh_cind[i];
    int val;
    if (c < KK) val = completed_seqs[((size_t)b * KK + c) * MAXLEN + pos];
    else {
      int k2 = c - KK;
      val = (pos < LL) ? cand_seqs[((size_t)b * KK + k2) * LL + pos] : EOSI;
    }
    out[O4 + ((size_t)b * KK + i) * MAXLEN + pos] = (float)val;
  }
}

// ---------------- Kernel 3: decoder-state gather (float4 copies) ----------------
__global__ __launch_bounds__(STHR) void k_gather(
    const float* __restrict__ ctx, const float* __restrict__ r1,
    const float* __restrict__ r2, const int* __restrict__ ws_par,
    float* __restrict__ out) {
  const int r = blockIdx.x;             // b*K + k
  const int b = r >> 3;
  const int src = (b << 3) + ws_par[r];
  const int tid = threadIdx.x;
  {
    const float4* s4 = (const float4*)(ctx + (size_t)src * AA);
    float4* d4 = (float4*)(out + O6 + (size_t)r * AA);
    for (int i = tid; i < AA / 4; i += STHR) d4[i] = s4[i];
  }
  {
    const float4* s4 = (const float4*)(r1 + (size_t)src * DD);
    float4* d4 = (float4*)(out + O7 + (size_t)r * DD);
    for (int i = tid; i < DD / 4; i += STHR) d4[i] = s4[i];
  }
  {
    const float4* s4 = (const float4*)(r2 + (size_t)src * DD);
    float4* d4 = (float4*)(out + O8 + (size_t)r * DD);
    for (int i = tid; i < DD / 4; i += STHR) d4[i] = s4[i];
  }
}

extern "C" void kernel_launch(void* const* d_in, const int* in_sizes, int n_in,
                              void* d_out, int out_size, void* d_ws, size_t ws_size,
                              hipStream_t stream) {
  const float* logits = (const float*)d_in[0];
  const float* cand_scores = (const float*)d_in[1];
  const int* cand_seqs = (const int*)d_in[2];
  const float* completed_scores = (const float*)d_in[3];
  const int* completed_seqs = (const int*)d_in[4];
  const int* completed_length = (const int*)d_in[5];
  const float* dctx = (const float*)d_in[6];
  const float* drnn1 = (const float*)d_in[7];
  const float* drnn2 = (const float*)d_in[8];
  float* out = (float*)d_out;

  float* ws_max = (float*)d_ws;                 // 1024
  float* ws_lse = ws_max + BB * KK;             // 1024
  float* ws_eos = ws_lse + BB * KK;             // 1024
  float* ws_tv = ws_eos + BB * KK;              // 8192
  int* ws_ti = (int*)(ws_tv + BB * KK * 8);     // 8192
  int* ws_par = ws_ti + BB * KK * 8;            // 1024

  k_rowpass<<<BB * KK, NTHR, 0, stream>>>(logits, ws_max, ws_lse, ws_eos, ws_tv, ws_ti);
  k_select<<<BB, STHR, 0, stream>>>(cand_scores, cand_seqs, completed_scores,
                                    completed_seqs, completed_length, ws_max, ws_lse,
                                    ws_eos, ws_tv, ws_ti, ws_par, out);
  k_gather<<<BB * KK, STHR, 0, stream>>>(dctx, drnn1, drnn2, ws_par, out);
}

// Round 7
// 349.187 us; speedup vs baseline: 1.1613x; 1.0089x over previous
//
#include <hip/hip_runtime.h>

// Beam-search step, B=128 K=8 V=50257 L=64 MAXL=128 A=512 D=1024 EOS=2.
// k_rowpass v5: pass A strip-mined into 8-deep NO-bounds-check load groups
// (8 KB in flight per wave -> memory-bound, not latency-bound); tau = 9th
// largest per-thread max; pass B rescans only qualifying threads (~2MB).

#define BB 128
#define KK 8
#define VV 50257
#define LL 64
#define MAXLEN 128
#define AA 512
#define DD 1024
#define EOSI 2
#define NTHR 256
#define NWAVE 4
#define CAP 1024
#define STHR 256

// output offsets (flat floats in d_out)
constexpr size_t O0 = 0;                      // new_cand_scores (B*K)
constexpr size_t O1 = 1024;                   // new_seqs (B*K*65)
constexpr size_t O2 = 67584;                  // parents (B*K)
constexpr size_t O3 = 68608;                  // comp_scores (B*K)
constexpr size_t O4 = 69632;                  // comp_seqs (B*K*128)
constexpr size_t O5 = 200704;                 // comp_len (B*K)
constexpr size_t O6 = 201728;                 // ctx (B*K*512)
constexpr size_t O7 = 726016;                 // rnn1 (B*K*1024)
constexpr size_t O8 = 1774592;                // rnn2 (B*K*1024)

__device__ __forceinline__ bool better(float v2, int i2, float v1, int i1) {
  // jax.lax.top_k order: descending value, ties -> lower index first
  return (v2 > v1) || (v2 == v1 && i2 < i1);
}

// ---------------- Kernel 1: per-(b,k)-row stats + top-8 via thread filter ----------------
__global__ __launch_bounds__(NTHR) void k_rowpass(
    const float* __restrict__ logits,
    float* __restrict__ ws_max, float* __restrict__ ws_lse,
    float* __restrict__ ws_eos,
    float* __restrict__ ws_tv, int* __restrict__ ws_ti) {
  const int r = blockIdx.x;              // r = b*K + k
  const int tid = threadIdx.x;
  const int lane = tid & 63, wid = tid >> 6;
  const float* __restrict__ row = logits + (size_t)r * VV;

  __shared__ float sm[NTHR];             // per-thread maxima
  __shared__ float redS[NWAVE], redM[NWAVE];
  __shared__ float stau;
  __shared__ int scnt;
  __shared__ float cv[CAP];
  __shared__ int ci[CAP];
  __shared__ float rv4[NWAVE]; __shared__ int ri4[NWAVE], rl4[NWAVE];

  if (tid == 0) { ws_eos[r] = row[EOSI]; scnt = 0; }
  __syncthreads();

  // alignment: (r*VV) mod 4 == r mod 4  (VV % 4 == 1)
  const int pre = (4 - (r & 3)) & 3;
  const int nvec = (VV - pre) >> 2;
  const int rem = VV - pre - (nvec << 2);
  const float4* __restrict__ vrow = (const float4*)(row + pre);

  float m = -INFINITY, s0 = 0.0f, s1 = 0.0f, s2 = 0.0f, s3 = 0.0f;

  // prologue/epilogue scalars (<=6 total): fold into sum/max and
  // force-collect as candidates (disjoint from the vrow range).
  if (tid < pre) {
    float x = row[tid];
    s0 += __expf(x); m = fmaxf(m, x);
    int p = atomicAdd(&scnt, 1); cv[p] = x; ci[p] = tid;
  }
  if (tid >= 8 && tid < 8 + rem) {
    int e = pre + (nvec << 2) + (tid - 8);
    float x = row[e];
    s0 += __expf(x); m = fmaxf(m, x);
    int p = atomicAdd(&scnt, 1); cv[p] = x; ci[p] = e;
  }

  // -------- pass A: 8-deep load groups, no bounds checks in main body --------
  // All 8 strided float4s of a group are provably < FULL <= nvec.
  const int FULL = nvec & ~(8 * NTHR - 1);     // multiple of 2048 (= 12288)
  for (int base = 0; base < FULL; base += 8 * NTHR) {
    float4 xs[8];
#pragma unroll
    for (int c = 0; c < 8; ++c) xs[c] = vrow[base + c * NTHR + tid];
#pragma unroll
    for (int c = 0; c < 8; ++c) {
      float4 x = xs[c];
      s0 += __expf(x.x); s1 += __expf(x.y);
      s2 += __expf(x.z); s3 += __expf(x.w);
      m = fmaxf(fmaxf(x.x, x.y), m);
      m = fmaxf(fmaxf(x.z, x.w), m);
    }
  }
  // tail (< 2048 float4s, <=2 bounds-checked iterations/thread)
  for (int i = FULL + tid; i < nvec; i += NTHR) {
    float4 x = vrow[i];
    s0 += __expf(x.x); s1 += __expf(x.y);
    s2 += __expf(x.z); s3 += __expf(x.w);
    m = fmaxf(fmaxf(x.x, x.y), m);
    m = fmaxf(fmaxf(x.z, x.w), m);
  }

  sm[tid] = m;                            // per-thread max (kept in m too)
  float s = (s0 + s1) + (s2 + s3);
  float mr = m;
  for (int off = 32; off; off >>= 1) {
    s += __shfl_down(s, off);
    mr = fmaxf(mr, __shfl_down(mr, off));
  }
  if (lane == 0) { redS[wid] = s; redM[wid] = mr; }
  __syncthreads();
  if (tid == 0) {
    float S = (redS[0] + redS[1]) + (redS[2] + redS[3]);
    float M = fmaxf(fmaxf(redM[0], redM[1]), fmaxf(redM[2], redM[3]));
    ws_max[r] = M;
    ws_lse[r] = logf(S) - M;   // == log(sum exp(x - M)) up to rounding
  }

  // -------- tau = 9th largest of the 256 per-thread maxima (wave 0) --------
  // At most 8 thread-maxima can exceed the true 8th-largest element, so the
  // 9th-largest thread-max <= true 8th-largest value; filtering >= tau keeps
  // all top-8, and >=9 distinct elements >= tau exist (>=8 non-EOS).
  if (wid == 0) {
    float v0 = sm[lane], v1 = sm[lane + 64], v2 = sm[lane + 128], v3 = sm[lane + 192];
    float tau = -INFINITY;
    for (int rr = 0; rr < 9; ++rr) {
      float lm = fmaxf(fmaxf(v0, v1), fmaxf(v2, v3));
      float wm = lm;
      for (int off = 32; off; off >>= 1) wm = fmaxf(wm, __shfl_down(wm, off));
      wm = __shfl(wm, 0);
      tau = wm;
      unsigned long long msk = __ballot(lm == wm);
      int first = __ffsll(msk) - 1;
      if (lane == first) {
        if (v0 == wm) v0 = -INFINITY;
        else if (v1 == wm) v1 = -INFINITY;
        else if (v2 == wm) v2 = -INFINITY;
        else v3 = -INFINITY;
      }
    }
    if (lane == 0) stau = tau;
  }
  __syncthreads();
  const float tau = stau;

  // -------- pass B: only qualifying threads rescan their own elements --------
  // (~9-12 threads/block; their float4s are L2/L3-resident from pass A)
  if (m >= tau) {
    for (int i = tid; i < nvec; i += NTHR) {
      float4 x = vrow[i];
      const int i0 = pre + (i << 2);
      if (x.x >= tau) { int p = atomicAdd(&scnt, 1); if (p < CAP) { cv[p] = x.x; ci[p] = i0; } }
      if (x.y >= tau) { int p = atomicAdd(&scnt, 1); if (p < CAP) { cv[p] = x.y; ci[p] = i0 + 1; } }
      if (x.z >= tau) { int p = atomicAdd(&scnt, 1); if (p < CAP) { cv[p] = x.z; ci[p] = i0 + 2; } }
      if (x.w >= tau) { int p = atomicAdd(&scnt, 1); if (p < CAP) { cv[p] = x.w; ci[p] = i0 + 3; } }
    }
  }
  __syncthreads();

  // -------- top-8 (value desc, index asc), excluding EOS --------
  const int n = scnt < CAP ? scnt : CAP;
  for (int sel = 0; sel < 8; ++sel) {
    float bv = -INFINITY; int bi = 0x7fffffff; int bl = -1;
    for (int j = tid; j < n; j += NTHR) {
      float v = cv[j]; int idx = ci[j];
      if (idx != EOSI && better(v, idx, bv, bi)) { bv = v; bi = idx; bl = j; }
    }
    for (int off = 32; off; off >>= 1) {
      float v2 = __shfl_down(bv, off);
      int i2 = __shfl_down(bi, off);
      int l2 = __shfl_down(bl, off);
      if (better(v2, i2, bv, bi)) { bv = v2; bi = i2; bl = l2; }
    }
    if (lane == 0) { rv4[wid] = bv; ri4[wid] = bi; rl4[wid] = bl; }
    __syncthreads();
    if (tid == 0) {
      float fv = rv4[0]; int fi = ri4[0], fl = rl4[0];
      for (int w = 1; w < NWAVE; ++w)
        if (better(rv4[w], ri4[w], fv, fi)) { fv = rv4[w]; fi = ri4[w]; fl = rl4[w]; }
      ws_tv[r * 8 + sel] = fv;
      ws_ti[r * 8 + sel] = fi;
      if (fl >= 0) cv[fl] = -INFINITY;
    }
    __syncthreads();
  }
}

// ---------------- Kernel 2: per-batch merge + small outputs ----------------
__global__ __launch_bounds__(STHR) void k_select(
    const float* __restrict__ cand_scores, const int* __restrict__ cand_seqs,
    const float* __restrict__ completed_scores, const int* __restrict__ completed_seqs,
    const int* __restrict__ completed_length,
    const float* __restrict__ ws_max, const float* __restrict__ ws_lse,
    const float* __restrict__ ws_eos, const float* __restrict__ ws_tv,
    const int* __restrict__ ws_ti, int* __restrict__ ws_par,
    float* __restrict__ out) {
  const int b = blockIdx.x;
  const int tid = threadIdx.x;
  __shared__ float sh_mx[KK], sh_lse[KK], sh_cand[KK];
  __shared__ float sh_ncs[KK]; __shared__ int sh_par[KK], sh_sym[KK];
  __shared__ float sh_cs[KK];  __shared__ int sh_clen[KK], sh_cind[KK];
  if (tid < KK) {
    sh_mx[tid] = ws_max[b * KK + tid];
    sh_lse[tid] = ws_lse[b * KK + tid];
    sh_cand[tid] = cand_scores[b * KK + tid];
  }
  __syncthreads();
  if (tid < 64) {
    const int lane = tid;
    // ---- candidate top-8 over 8 rows x 8 entries ----
    const int k = lane >> 3, j = lane & 7;
    float x = ws_tv[(b * KK + k) * 8 + j];
    int v = ws_ti[(b * KK + k) * 8 + j];
    // match jax association: ((x - max) - lse) + cand
    float val = ((x - sh_mx[k]) - sh_lse[k]) + sh_cand[k];
    int flat = k * VV + v;
    if (v == 0x7fffffff) { val = -INFINITY; flat = 0x7fffffff; }
    for (int sel = 0; sel < 8; ++sel) {
      float bv = val; int bi = flat; int bl = lane;
      for (int off = 32; off; off >>= 1) {
        float v2 = __shfl_down(bv, off);
        int i2 = __shfl_down(bi, off);
        int l2 = __shfl_down(bl, off);
        if (better(v2, i2, bv, bi)) { bv = v2; bi = i2; bl = l2; }
      }
      int wl = __shfl(bl, 0);
      if (lane == wl) {
        sh_ncs[sel] = val; sh_par[sel] = flat / VV; sh_sym[sel] = flat % VV;
        val = -INFINITY; flat = 0x7fffffff;
      }
    }
    // ---- completed top-8 over 16 rescaled scores ----
    float cs; int clen;
    if (lane < KK) {
      cs = completed_scores[b * KK + lane];
      clen = completed_length[b * KK + lane];
    } else if (lane < 2 * KK) {
      int k2 = lane - KK;
      cs = ((ws_eos[b * KK + k2] - sh_mx[k2]) - sh_lse[k2]) + sh_cand[k2];
      clen = LL + 1;
    } else { cs = -INFINITY; clen = 1; }
    float rsc = (lane < 2 * KK) ? cs / (float)clen : -INFINITY;
    for (int sel = 0; sel < 8; ++sel) {
      float bv = rsc; int bi = lane;
      for (int off = 32; off; off >>= 1) {
        float v2 = __shfl_down(bv, off);
        int i2 = __shfl_down(bi, off);
        if (better(v2, i2, bv, bi)) { bv = v2; bi = i2; }
      }
      int wl = __shfl(bi, 0);
      if (lane == wl) {
        sh_cs[sel] = cs; sh_clen[sel] = clen; sh_cind[sel] = lane;
        rsc = -INFINITY;
      }
    }
  }
  __syncthreads();
  if (tid < KK) {
    out[O0 + (size_t)b * KK + tid] = sh_ncs[tid];
    out[O2 + (size_t)b * KK + tid] = (float)sh_par[tid];
    out[O3 + (size_t)b * KK + tid] = sh_cs[tid];
    out[O5 + (size_t)b * KK + tid] = (float)sh_clen[tid];
    ws_par[b * KK + tid] = sh_par[tid];
  }
  // new_seqs: K * (L+1), gather parent prefix + new symbol
  for (int t = tid; t < KK * (LL + 1); t += STHR) {
    int i = t / (LL + 1), pos = t - i * (LL + 1);
    int val;
    if (pos < LL) val = cand_seqs[((size_t)b * KK + sh_par[i]) * LL + pos];
    else val = sh_sym[i];
    out[O1 + ((size_t)b * KK + i) * (LL + 1) + pos] = (float)val;
  }
  // comp_seqs: K * MAXL
  for (int t = tid; t < KK * MAXLEN; t += STHR) {
    int i = t >> 7, pos = t & 127;
    int c = sh_cind[i];
    int val;
    if (c < KK) val = completed_seqs[((size_t)b * KK + c) * MAXLEN + pos];
    else {
      int k2 = c - KK;
      val = (pos < LL) ? cand_seqs[((size_t)b * KK + k2) * LL + pos] : EOSI;
    }
    out[O4 + ((size_t)b * KK + i) * MAXLEN + pos] = (float)val;
  }
}

// ---------------- Kernel 3: decoder-state gather (float4 copies) ----------------
__global__ __launch_bounds__(STHR) void k_gather(
    const float* __restrict__ ctx, const float* __restrict__ r1,
    const float* __restrict__ r2, const int* __restrict__ ws_par,
    float* __restrict__ out) {
  const int r = blockIdx.x;             // b*K + k
  const int b = r >> 3;
  const int src = (b << 3) + ws_par[r];
  const int tid = threadIdx.x;
  {
    const float4* s4 = (const float4*)(ctx + (size_t)src * AA);
    float4* d4 = (float4*)(out + O6 + (size_t)r * AA);
    for (int i = tid; i < AA / 4; i += STHR) d4[i] = s4[i];
  }
  {
    const float4* s4 = (const float4*)(r1 + (size_t)src * DD);
    float4* d4 = (float4*)(out + O7 + (size_t)r * DD);
    for (int i = tid; i < DD / 4; i += STHR) d4[i] = s4[i];
  }
  {
    const float4* s4 = (const float4*)(r2 + (size_t)src * DD);
    float4* d4 = (float4*)(out + O8 + (size_t)r * DD);
    for (int i = tid; i < DD / 4; i += STHR) d4[i] = s4[i];
  }
}

extern "C" void kernel_launch(void* const* d_in, const int* in_sizes, int n_in,
                              void* d_out, int out_size, void* d_ws, size_t ws_size,
                              hipStream_t stream) {
  const float* logits = (const float*)d_in[0];
  const float* cand_scores = (const float*)d_in[1];
  const int* cand_seqs = (const int*)d_in[2];
  const float* completed_scores = (const float*)d_in[3];
  const int* completed_seqs = (const int*)d_in[4];
  const int* completed_length = (const int*)d_in[5];
  const float* dctx = (const float*)d_in[6];
  const float* drnn1 = (const float*)d_in[7];
  const float* drnn2 = (const float*)d_in[8];
  float* out = (float*)d_out;

  float* ws_max = (float*)d_ws;                 // 1024
  float* ws_lse = ws_max + BB * KK;             // 1024
  float* ws_eos = ws_lse + BB * KK;             // 1024
  float* ws_tv = ws_eos + BB * KK;              // 8192
  int* ws_ti = (int*)(ws_tv + BB * KK * 8);     // 8192
  int* ws_par = ws_ti + BB * KK * 8;            // 1024

  k_rowpass<<<BB * KK, NTHR, 0, stream>>>(logits, ws_max, ws_lse, ws_eos, ws_tv, ws_ti);
  k_select<<<BB, STHR, 0, stream>>>(cand_scores, cand_seqs, completed_scores,
                                    completed_seqs, completed_length, ws_max, ws_lse,
                                    ws_eos, ws_tv, ws_ti, ws_par, out);
  k_gather<<<BB * KK, STHR, 0, stream>>>(dctx, drnn1, drnn2, ws_par, out);
}